// Round 1
// baseline (335.846 us; speedup 1.0000x reference)
//
#include <hip/hip_runtime.h>
#include <hip/hip_bf16.h>

#define N 8192
#define D 512
#define BM 128
#define BK 64

typedef __attribute__((ext_vector_type(4))) float f32x4;
typedef __attribute__((ext_vector_type(8))) short bf16x8;

__device__ __forceinline__ void g2l16(const void* g, void* l) {
  __builtin_amdgcn_global_load_lds(
      (const __attribute__((address_space(1))) void*)g,
      (__attribute__((address_space(3))) void*)l, 16, 0, 0);
}

__device__ __forceinline__ unsigned short f32_to_bf16(float f) {
  unsigned int u = __float_as_uint(f);
  unsigned int r = (u + 0x7fffu + ((u >> 16) & 1u)) >> 16;
  return (unsigned short)r;
}

// One block per row (of X for bid<N, of Y for bid>=N): convert f32->bf16 (RNE),
// compute row squared norm FROM THE ROUNDED VALUES (keeps diagonal d2 ~ 0).
__global__ __launch_bounds__(128) void prep_kernel(
    const float* __restrict__ X, const float* __restrict__ Y,
    unsigned short* __restrict__ Xb, unsigned short* __restrict__ Yb,
    float* __restrict__ sqX, float* __restrict__ sqY) {
  const int b = blockIdx.x;
  const int row = b & (N - 1);
  const float* src = (b < N) ? X : Y;
  unsigned short* dst = (b < N) ? Xb : Yb;
  float* sq = (b < N) ? sqX : sqY;
  const int t = threadIdx.x;  // 128 threads * 4 floats = 512
  float4 v = reinterpret_cast<const float4*>(src + (size_t)row * D)[t];
  unsigned short b0 = f32_to_bf16(v.x), b1 = f32_to_bf16(v.y),
                 b2 = f32_to_bf16(v.z), b3 = f32_to_bf16(v.w);
  float f0 = __uint_as_float((unsigned)b0 << 16);
  float f1 = __uint_as_float((unsigned)b1 << 16);
  float f2 = __uint_as_float((unsigned)b2 << 16);
  float f3 = __uint_as_float((unsigned)b3 << 16);
  float s = f0 * f0 + f1 * f1 + f2 * f2 + f3 * f3;
  ushort4 o; o.x = b0; o.y = b1; o.z = b2; o.w = b3;
  reinterpret_cast<ushort4*>(dst + (size_t)row * D)[t] = o;
  #pragma unroll
  for (int msk = 1; msk < 64; msk <<= 1) s += __shfl_xor(s, msk);
  __shared__ float red[2];
  if ((t & 63) == 0) red[t >> 6] = s;
  __syncthreads();
  if (t == 0) sq[row] = red[0] + red[1];
}

// Fused dual-GEMM + RBF + reductions. 128x128 tile per block, 4 waves (2x2),
// each wave owns a 64x64 sub-tile of both Gram matrices.
__global__ __launch_bounds__(256, 2) void hsic_main(
    const unsigned short* __restrict__ Xb, const unsigned short* __restrict__ Yb,
    const float* __restrict__ sqX, const float* __restrict__ sqY,
    float* __restrict__ rowK, float* __restrict__ rowL,
    float* __restrict__ sums) {
  __shared__ __align__(16) unsigned short sXi[BM * BK];
  __shared__ __align__(16) unsigned short sXj[BM * BK];
  __shared__ __align__(16) unsigned short sYi[BM * BK];
  __shared__ __align__(16) unsigned short sYj[BM * BK];

  const int bid = blockIdx.x;
  const int ti = bid >> 6, tj = bid & 63;
  const int ib = ti * BM, jb = tj * BM;
  const int t = threadIdx.x;
  const int lane = t & 63, wave = t >> 6;
  const int wr = wave >> 1, wc = wave & 1;
  const int fr = lane & 15, fq = lane >> 4;

  f32x4 accK[4][4], accL[4][4];
  #pragma unroll
  for (int m = 0; m < 4; ++m)
    #pragma unroll
    for (int n = 0; n < 4; ++n) { accK[m][n] = (f32x4)0.f; accL[m][n] = (f32x4)0.f; }

  const unsigned short* s0 = Xb + (size_t)ib * D;
  const unsigned short* s1 = Xb + (size_t)jb * D;
  const unsigned short* s2 = Yb + (size_t)ib * D;
  const unsigned short* s3 = Yb + (size_t)jb * D;

  const int srow = t >> 3;        // 0..31
  const int scol = (t & 7) * 8;   // 0..56 (8 bf16 = 16B per issue)

  for (int kt = 0; kt < D / BK; ++kt) {
    const int kb = kt * BK;
    #pragma unroll
    for (int q = 0; q < 4; ++q) {
      const int row = q * 32 + srow;
      const size_t goff = (size_t)row * D + kb + scol;
      const int loff = q * 2048 + t * 8;
      g2l16(s0 + goff, sXi + loff);
      g2l16(s1 + goff, sXj + loff);
      g2l16(s2 + goff, sYi + loff);
      g2l16(s3 + goff, sYj + loff);
    }
    __syncthreads();
    #pragma unroll
    for (int kk = 0; kk < 2; ++kk) {
      const int ko = kk * 32 + fq * 8;
      bf16x8 a[4], b[4];
      #pragma unroll
      for (int m = 0; m < 4; ++m)
        a[m] = *(const bf16x8*)&sXi[(wr * 64 + m * 16 + fr) * BK + ko];
      #pragma unroll
      for (int n = 0; n < 4; ++n)
        b[n] = *(const bf16x8*)&sXj[(wc * 64 + n * 16 + fr) * BK + ko];
      #pragma unroll
      for (int m = 0; m < 4; ++m)
        #pragma unroll
        for (int n = 0; n < 4; ++n)
          accK[m][n] = __builtin_amdgcn_mfma_f32_16x16x32_bf16(a[m], b[n], accK[m][n], 0, 0, 0);
      #pragma unroll
      for (int m = 0; m < 4; ++m)
        a[m] = *(const bf16x8*)&sYi[(wr * 64 + m * 16 + fr) * BK + ko];
      #pragma unroll
      for (int n = 0; n < 4; ++n)
        b[n] = *(const bf16x8*)&sYj[(wc * 64 + n * 16 + fr) * BK + ko];
      #pragma unroll
      for (int m = 0; m < 4; ++m)
        #pragma unroll
        for (int n = 0; n < 4; ++n)
          accL[m][n] = __builtin_amdgcn_mfma_f32_16x16x32_bf16(a[m], b[n], accL[m][n], 0, 0, 0);
    }
    __syncthreads();
  }

  // Epilogue: K = exp(-0.5*max(sq_i + sq_j - 2*G, 0)) for both matrices,
  // accumulate sum(K*L), row sums of K and L.
  float sxj[4], syj[4];
  #pragma unroll
  for (int n = 0; n < 4; ++n) {
    const int j = jb + wc * 64 + n * 16 + fr;
    sxj[n] = sqX[j];
    syj[n] = sqY[j];
  }
  float kl = 0.f;
  #pragma unroll
  for (int m = 0; m < 4; ++m) {
    #pragma unroll
    for (int r = 0; r < 4; ++r) {
      const int i = ib + wr * 64 + m * 16 + fq * 4 + r;
      const float sxi = sqX[i], syi = sqY[i];
      float rk = 0.f, rl = 0.f;
      #pragma unroll
      for (int n = 0; n < 4; ++n) {
        float dK = fmaxf(sxi + sxj[n] - 2.f * accK[m][n][r], 0.f);
        float Kv = __expf(-0.5f * dK);
        float dL = fmaxf(syi + syj[n] - 2.f * accL[m][n][r], 0.f);
        float Lv = __expf(-0.5f * dL);
        kl += Kv * Lv;
        rk += Kv;
        rl += Lv;
      }
      // reduce across the 16 lanes covering this row's 16 columns
      #pragma unroll
      for (int msk = 1; msk < 16; msk <<= 1) {
        rk += __shfl_xor(rk, msk);
        rl += __shfl_xor(rl, msk);
      }
      if (fr == 0) {
        atomicAdd(&rowK[i], rk);
        atomicAdd(&rowL[i], rl);
      }
    }
  }
  #pragma unroll
  for (int msk = 1; msk < 64; msk <<= 1) kl += __shfl_xor(kl, msk);
  __shared__ float klred[4];
  if (lane == 0) klred[wave] = kl;
  __syncthreads();
  if (t == 0) atomicAdd(sums, klred[0] + klred[1] + klred[2] + klred[3]);
}

__global__ __launch_bounds__(256) void finalize_kernel(
    const float* __restrict__ rowK, const float* __restrict__ rowL,
    const float* __restrict__ sums, float* __restrict__ out) {
  const int t = threadIdx.x;
  float dp = 0.f, sk = 0.f, sl = 0.f;
  for (int i = t; i < N; i += 256) {
    float a = rowK[i], b = rowL[i];
    dp += a * b; sk += a; sl += b;
  }
  #pragma unroll
  for (int msk = 1; msk < 64; msk <<= 1) {
    dp += __shfl_xor(dp, msk);
    sk += __shfl_xor(sk, msk);
    sl += __shfl_xor(sl, msk);
  }
  __shared__ float r[3][4];
  const int wave = t >> 6, lane = t & 63;
  if (lane == 0) { r[0][wave] = dp; r[1][wave] = sk; r[2][wave] = sl; }
  __syncthreads();
  if (t == 0) {
    float DP = r[0][0] + r[0][1] + r[0][2] + r[0][3];
    float SK = r[1][0] + r[1][1] + r[1][2] + r[1][3];
    float SL = r[2][0] + r[2][1] + r[2][2] + r[2][3];
    const float n = (float)N;
    float raw = sums[0] - (2.f / n) * DP + (SK / n) * (SL / n);
    out[0] = raw / ((n - 1.f) * (n - 1.f));
  }
}

extern "C" void kernel_launch(void* const* d_in, const int* in_sizes, int n_in,
                              void* d_out, int out_size, void* d_ws, size_t ws_size,
                              hipStream_t stream) {
  const float* X = (const float*)d_in[0];
  const float* Y = (const float*)d_in[1];
  char* ws = (char*)d_ws;
  unsigned short* Xb = (unsigned short*)ws;                       // 8 MB
  unsigned short* Yb = (unsigned short*)(ws + (size_t)N * D * 2); // 8 MB
  float* sqX = (float*)(ws + (size_t)N * D * 4);
  float* sqY = sqX + N;
  float* rowK = sqY + N;
  float* rowL = rowK + N;
  float* sums = rowL + N;

  hipMemsetAsync(rowK, 0, (size_t)(2 * N + 16) * sizeof(float), stream);
  prep_kernel<<<2 * N, 128, 0, stream>>>(X, Y, Xb, Yb, sqX, sqY);
  hsic_main<<<(N / BM) * (N / BM), 256, 0, stream>>>(Xb, Yb, sqX, sqY, rowK, rowL, sums);
  finalize_kernel<<<1, 256, 0, stream>>>(rowK, rowL, sums, (float*)d_out);
}

// Round 2
// 187.671 us; speedup vs baseline: 1.7895x; 1.7895x over previous
//
#include <hip/hip_runtime.h>
#include <hip/hip_bf16.h>

#define N 8192
#define D 512
#define BM 128
#define BK 64

typedef __attribute__((ext_vector_type(4))) float f32x4;
typedef __attribute__((ext_vector_type(8))) short bf16x8;

__device__ __forceinline__ void g2l16(const void* g, void* l) {
  __builtin_amdgcn_global_load_lds(
      (const __attribute__((address_space(1))) void*)g,
      (__attribute__((address_space(3))) void*)l, 16, 0, 0);
}

__device__ __forceinline__ unsigned short f32_to_bf16(float f) {
  unsigned int u = __float_as_uint(f);
  unsigned int r = (u + 0x7fffu + ((u >> 16) & 1u)) >> 16;
  return (unsigned short)r;
}

// XOR-swizzled LDS element offset for a [row][64 bf16] tile (row stride 128B).
// byte_col ^= (row&7)<<4 spreads the 16 fr-lanes over 8 distinct 16B slots.
__device__ __forceinline__ int lds_off(int row, int kobyte) {
  return row * BK + ((kobyte ^ ((row & 7) << 4)) >> 1);
}

// One block per row (of X for bid<N, of Y for bid>=N): convert f32->bf16 (RNE),
// compute row squared norm FROM THE ROUNDED VALUES (keeps diagonal d2 ~ 0).
__global__ __launch_bounds__(128) void prep_kernel(
    const float* __restrict__ X, const float* __restrict__ Y,
    unsigned short* __restrict__ Xb, unsigned short* __restrict__ Yb,
    float* __restrict__ sqX, float* __restrict__ sqY) {
  const int b = blockIdx.x;
  const int row = b & (N - 1);
  const float* src = (b < N) ? X : Y;
  unsigned short* dst = (b < N) ? Xb : Yb;
  float* sq = (b < N) ? sqX : sqY;
  const int t = threadIdx.x;  // 128 threads * 4 floats = 512
  float4 v = reinterpret_cast<const float4*>(src + (size_t)row * D)[t];
  unsigned short b0 = f32_to_bf16(v.x), b1 = f32_to_bf16(v.y),
                 b2 = f32_to_bf16(v.z), b3 = f32_to_bf16(v.w);
  float f0 = __uint_as_float((unsigned)b0 << 16);
  float f1 = __uint_as_float((unsigned)b1 << 16);
  float f2 = __uint_as_float((unsigned)b2 << 16);
  float f3 = __uint_as_float((unsigned)b3 << 16);
  float s = f0 * f0 + f1 * f1 + f2 * f2 + f3 * f3;
  ushort4 o; o.x = b0; o.y = b1; o.z = b2; o.w = b3;
  reinterpret_cast<ushort4*>(dst + (size_t)row * D)[t] = o;
  #pragma unroll
  for (int msk = 1; msk < 64; msk <<= 1) s += __shfl_xor(s, msk);
  __shared__ float red[2];
  if ((t & 63) == 0) red[t >> 6] = s;
  __syncthreads();
  if (t == 0) sq[row] = red[0] + red[1];
}

// Fused dual-GEMM + RBF + reductions over the UPPER TRIANGLE of tiles only.
// 128x128 tile per block, 4 waves (2x2), each wave owns 64x64 of both Grams.
__global__ __launch_bounds__(256, 2) void hsic_main(
    const unsigned short* __restrict__ Xb, const unsigned short* __restrict__ Yb,
    const float* __restrict__ sqX, const float* __restrict__ sqY,
    float* __restrict__ rowK, float* __restrict__ rowL,
    float* __restrict__ sums) {
  __shared__ __align__(16) unsigned short sXi[BM * BK];
  __shared__ __align__(16) unsigned short sXj[BM * BK];
  __shared__ __align__(16) unsigned short sYi[BM * BK];
  __shared__ __align__(16) unsigned short sYj[BM * BK];

  // Decode upper-triangle tile (ti <= tj) from linear bid. cnt(r)=r*(129-r)/2.
  const int bid = blockIdx.x;
  int ti = (int)((129.0f - sqrtf(16641.0f - 8.0f * (float)bid)) * 0.5f);
  while (ti > 0 && (ti * (129 - ti)) / 2 > bid) --ti;
  while (((ti + 1) * (128 - ti)) / 2 <= bid) ++ti;
  const int tj = ti + (bid - (ti * (129 - ti)) / 2);
  const bool diag = (ti == tj);

  const int ib = ti * BM, jb = tj * BM;
  const int t = threadIdx.x;
  const int lane = t & 63, wave = t >> 6;
  const int wr = wave >> 1, wc = wave & 1;
  const int fr = lane & 15, fq = lane >> 4;

  f32x4 accK[4][4], accL[4][4];
  #pragma unroll
  for (int m = 0; m < 4; ++m)
    #pragma unroll
    for (int n = 0; n < 4; ++n) { accK[m][n] = (f32x4)0.f; accL[m][n] = (f32x4)0.f; }

  const unsigned short* s0 = Xb + (size_t)ib * D;
  const unsigned short* s1 = Xb + (size_t)jb * D;
  const unsigned short* s2 = Yb + (size_t)ib * D;
  const unsigned short* s3 = Yb + (size_t)jb * D;

  const int srow = t >> 3;                         // 0..31
  const int scb = (t & 7) * 16;                    // byte col within row
  const int swcb = scb ^ ((srow & 7) << 4);        // pre-swizzled global col

  for (int kt = 0; kt < D / BK; ++kt) {
    const int kb = kt * BK;
    #pragma unroll
    for (int q = 0; q < 4; ++q) {
      const int row = q * 32 + srow;
      const size_t goff = (size_t)row * D + kb + (swcb >> 1);
      const int loff = q * 2048 + t * 8;           // linear LDS dest (elements)
      g2l16(s0 + goff, sXi + loff);
      g2l16(s1 + goff, sXj + loff);
      g2l16(s2 + goff, sYi + loff);
      g2l16(s3 + goff, sYj + loff);
    }
    __syncthreads();
    #pragma unroll
    for (int kk = 0; kk < 2; ++kk) {
      const int kob = kk * 64 + fq * 16;           // byte col of this frag
      bf16x8 a[4], b[4];
      #pragma unroll
      for (int m = 0; m < 4; ++m)
        a[m] = *(const bf16x8*)&sXi[lds_off(wr * 64 + m * 16 + fr, kob)];
      #pragma unroll
      for (int n = 0; n < 4; ++n)
        b[n] = *(const bf16x8*)&sXj[lds_off(wc * 64 + n * 16 + fr, kob)];
      #pragma unroll
      for (int m = 0; m < 4; ++m)
        #pragma unroll
        for (int n = 0; n < 4; ++n)
          accK[m][n] = __builtin_amdgcn_mfma_f32_16x16x32_bf16(a[m], b[n], accK[m][n], 0, 0, 0);
      #pragma unroll
      for (int m = 0; m < 4; ++m)
        a[m] = *(const bf16x8*)&sYi[lds_off(wr * 64 + m * 16 + fr, kob)];
      #pragma unroll
      for (int n = 0; n < 4; ++n)
        b[n] = *(const bf16x8*)&sYj[lds_off(wc * 64 + n * 16 + fr, kob)];
      #pragma unroll
      for (int m = 0; m < 4; ++m)
        #pragma unroll
        for (int n = 0; n < 4; ++n)
          accL[m][n] = __builtin_amdgcn_mfma_f32_16x16x32_bf16(a[m], b[n], accL[m][n], 0, 0, 0);
    }
    __syncthreads();
  }

  // Epilogue: K = exp(-0.5*max(sq_i + sq_j - 2*G, 0)) for both matrices.
  // Off-diagonal tiles stand for BOTH (i,j) and (j,i): weight 2 in kl,
  // and column sums feed rowK/rowL[j].
  float sxj[4], syj[4];
  #pragma unroll
  for (int n = 0; n < 4; ++n) {
    const int j = jb + wc * 64 + n * 16 + fr;
    sxj[n] = sqX[j];
    syj[n] = sqY[j];
  }
  float kl = 0.f;
  float ckK[4] = {0.f, 0.f, 0.f, 0.f}, ckL[4] = {0.f, 0.f, 0.f, 0.f};
  #pragma unroll
  for (int m = 0; m < 4; ++m) {
    #pragma unroll
    for (int r = 0; r < 4; ++r) {
      const int i = ib + wr * 64 + m * 16 + fq * 4 + r;
      const float sxi = sqX[i], syi = sqY[i];
      float rk = 0.f, rl = 0.f;
      #pragma unroll
      for (int n = 0; n < 4; ++n) {
        float dK = fmaxf(sxi + sxj[n] - 2.f * accK[m][n][r], 0.f);
        float Kv = __expf(-0.5f * dK);
        float dL = fmaxf(syi + syj[n] - 2.f * accL[m][n][r], 0.f);
        float Lv = __expf(-0.5f * dL);
        kl += Kv * Lv;
        rk += Kv; rl += Lv;
        ckK[n] += Kv; ckL[n] += Lv;
      }
      #pragma unroll
      for (int msk = 1; msk < 16; msk <<= 1) {
        rk += __shfl_xor(rk, msk);
        rl += __shfl_xor(rl, msk);
      }
      if (fr == 0) {
        atomicAdd(&rowK[i], rk);
        atomicAdd(&rowL[i], rl);
      }
    }
  }
  if (!diag) {
    #pragma unroll
    for (int n = 0; n < 4; ++n) {
      float a = ckK[n], b = ckL[n];
      a += __shfl_xor(a, 16); a += __shfl_xor(a, 32);
      b += __shfl_xor(b, 16); b += __shfl_xor(b, 32);
      if (fq == 0) {
        const int j = jb + wc * 64 + n * 16 + fr;
        atomicAdd(&rowK[j], a);
        atomicAdd(&rowL[j], b);
      }
    }
    kl *= 2.f;
  }
  #pragma unroll
  for (int msk = 1; msk < 64; msk <<= 1) kl += __shfl_xor(kl, msk);
  __shared__ float klred[4];
  if (lane == 0) klred[wave] = kl;
  __syncthreads();
  if (t == 0) atomicAdd(sums, klred[0] + klred[1] + klred[2] + klred[3]);
}

__global__ __launch_bounds__(256) void finalize_kernel(
    const float* __restrict__ rowK, const float* __restrict__ rowL,
    const float* __restrict__ sums, float* __restrict__ out) {
  const int t = threadIdx.x;
  float dp = 0.f, sk = 0.f, sl = 0.f;
  for (int i = t; i < N; i += 256) {
    float a = rowK[i], b = rowL[i];
    dp += a * b; sk += a; sl += b;
  }
  #pragma unroll
  for (int msk = 1; msk < 64; msk <<= 1) {
    dp += __shfl_xor(dp, msk);
    sk += __shfl_xor(sk, msk);
    sl += __shfl_xor(sl, msk);
  }
  __shared__ float r[3][4];
  const int wave = t >> 6, lane = t & 63;
  if (lane == 0) { r[0][wave] = dp; r[1][wave] = sk; r[2][wave] = sl; }
  __syncthreads();
  if (t == 0) {
    float DP = r[0][0] + r[0][1] + r[0][2] + r[0][3];
    float SK = r[1][0] + r[1][1] + r[1][2] + r[1][3];
    float SL = r[2][0] + r[2][1] + r[2][2] + r[2][3];
    const float n = (float)N;
    float raw = sums[0] - (2.f / n) * DP + (SK / n) * (SL / n);
    out[0] = raw / ((n - 1.f) * (n - 1.f));
  }
}

extern "C" void kernel_launch(void* const* d_in, const int* in_sizes, int n_in,
                              void* d_out, int out_size, void* d_ws, size_t ws_size,
                              hipStream_t stream) {
  const float* X = (const float*)d_in[0];
  const float* Y = (const float*)d_in[1];
  char* ws = (char*)d_ws;
  unsigned short* Xb = (unsigned short*)ws;                       // 8 MB
  unsigned short* Yb = (unsigned short*)(ws + (size_t)N * D * 2); // 8 MB
  float* sqX = (float*)(ws + (size_t)N * D * 4);
  float* sqY = sqX + N;
  float* rowK = sqY + N;
  float* rowL = rowK + N;
  float* sums = rowL + N;

  hipMemsetAsync(rowK, 0, (size_t)(2 * N + 16) * sizeof(float), stream);
  prep_kernel<<<2 * N, 128, 0, stream>>>(X, Y, Xb, Yb, sqX, sqY);
  const int ntiles = (N / BM) * (N / BM + 1) / 2;  // 2080 upper-triangle tiles
  hsic_main<<<ntiles, 256, 0, stream>>>(Xb, Yb, sqX, sqY, rowK, rowL, sums);
  finalize_kernel<<<1, 256, 0, stream>>>(rowK, rowL, sums, (float*)d_out);
}

// Round 5
// 175.932 us; speedup vs baseline: 1.9089x; 1.0667x over previous
//
#include <hip/hip_runtime.h>
#include <hip/hip_bf16.h>

#define N 8192
#define D 512
#define BM 128
#define BK 64

typedef __attribute__((ext_vector_type(4))) float f32x4;
typedef __attribute__((ext_vector_type(8))) short bf16x8;

__device__ __forceinline__ void g2l16(const void* g, void* l) {
  __builtin_amdgcn_global_load_lds(
      (const __attribute__((address_space(1))) void*)g,
      (__attribute__((address_space(3))) void*)l, 16, 0, 0);
}

__device__ __forceinline__ unsigned short f32_to_bf16(float f) {
  unsigned int u = __float_as_uint(f);
  unsigned int r = (u + 0x7fffu + ((u >> 16) & 1u)) >> 16;
  return (unsigned short)r;
}

// XOR-swizzled LDS element offset for a [row][64 bf16] tile (row stride 128B).
__device__ __forceinline__ int lds_off(int row, int kobyte) {
  return row * BK + ((kobyte ^ ((row & 7) << 4)) >> 1);
}

__global__ __launch_bounds__(128) void prep_kernel(
    const float* __restrict__ X, const float* __restrict__ Y,
    unsigned short* __restrict__ Xb, unsigned short* __restrict__ Yb,
    float* __restrict__ sqX, float* __restrict__ sqY) {
  const int b = blockIdx.x;
  const int row = b & (N - 1);
  const float* src = (b < N) ? X : Y;
  unsigned short* dst = (b < N) ? Xb : Yb;
  float* sq = (b < N) ? sqX : sqY;
  const int t = threadIdx.x;
  float4 v = reinterpret_cast<const float4*>(src + (size_t)row * D)[t];
  unsigned short b0 = f32_to_bf16(v.x), b1 = f32_to_bf16(v.y),
                 b2 = f32_to_bf16(v.z), b3 = f32_to_bf16(v.w);
  float f0 = __uint_as_float((unsigned)b0 << 16);
  float f1 = __uint_as_float((unsigned)b1 << 16);
  float f2 = __uint_as_float((unsigned)b2 << 16);
  float f3 = __uint_as_float((unsigned)b3 << 16);
  float s = f0 * f0 + f1 * f1 + f2 * f2 + f3 * f3;
  ushort4 o; o.x = b0; o.y = b1; o.z = b2; o.w = b3;
  reinterpret_cast<ushort4*>(dst + (size_t)row * D)[t] = o;
  #pragma unroll
  for (int msk = 1; msk < 64; msk <<= 1) s += __shfl_xor(s, msk);
  __shared__ float red[2];
  if ((t & 63) == 0) red[t >> 6] = s;
  __syncthreads();
  if (t == 0) sq[row] = red[0] + red[1];
}

// Fused dual-GEMM + RBF + reductions, upper-triangle tiles, 2-phase pipeline:
// X-MFMAs overlap the next X staging; Y-MFMAs overlap the next Y staging.
// vmcnt never drains to 0 inside the loop (T3/T4-lite); raw s_barrier only.
__global__ __launch_bounds__(256, 2) void hsic_main(
    const unsigned short* __restrict__ Xb, const unsigned short* __restrict__ Yb,
    const float* __restrict__ sqX, const float* __restrict__ sqY,
    float* __restrict__ rowK, float* __restrict__ rowL,
    float* __restrict__ sums) {
  __shared__ __align__(16) unsigned short sXi[BM * BK];
  __shared__ __align__(16) unsigned short sXj[BM * BK];
  __shared__ __align__(16) unsigned short sYi[BM * BK];
  __shared__ __align__(16) unsigned short sYj[BM * BK];

  const int bid = blockIdx.x;
  int ti = (int)((129.0f - sqrtf(16641.0f - 8.0f * (float)bid)) * 0.5f);
  while (ti > 0 && (ti * (129 - ti)) / 2 > bid) --ti;
  while (((ti + 1) * (128 - ti)) / 2 <= bid) ++ti;
  const int tj = ti + (bid - (ti * (129 - ti)) / 2);
  const bool diag = (ti == tj);

  const int ib = ti * BM, jb = tj * BM;
  const int t = threadIdx.x;
  const int lane = t & 63, wave = t >> 6;
  const int wr = wave >> 1, wc = wave & 1;
  const int fr = lane & 15, fq = lane >> 4;

  f32x4 accK[4][4], accL[4][4];
  #pragma unroll
  for (int m = 0; m < 4; ++m)
    #pragma unroll
    for (int n = 0; n < 4; ++n) { accK[m][n] = (f32x4)0.f; accL[m][n] = (f32x4)0.f; }

  const unsigned short* s0 = Xb + (size_t)ib * D;
  const unsigned short* s1 = Xb + (size_t)jb * D;
  const unsigned short* s2 = Yb + (size_t)ib * D;
  const unsigned short* s3 = Yb + (size_t)jb * D;

  const int srow = t >> 3;
  const int scb = (t & 7) * 16;
  const int swcb = scb ^ ((srow & 7) << 4);

  // 8 vmem issues per stage call (4 per buffer).
  auto stageX = [&](int kt) {
    const int kb = kt * BK;
    #pragma unroll
    for (int q = 0; q < 4; ++q) {
      const int row = q * 32 + srow;
      const size_t goff = (size_t)row * D + kb + (swcb >> 1);
      const int loff = q * 2048 + t * 8;
      g2l16(s0 + goff, sXi + loff);
      g2l16(s1 + goff, sXj + loff);
    }
  };
  auto stageY = [&](int kt) {
    const int kb = kt * BK;
    #pragma unroll
    for (int q = 0; q < 4; ++q) {
      const int row = q * 32 + srow;
      const size_t goff = (size_t)row * D + kb + (swcb >> 1);
      const int loff = q * 2048 + t * 8;
      g2l16(s2 + goff, sYi + loff);
      g2l16(s3 + goff, sYj + loff);
    }
  };

  bf16x8 a[2][4], b[2][4];
  auto loadFrags = [&](const unsigned short* si, const unsigned short* sj) {
    #pragma unroll
    for (int kk = 0; kk < 2; ++kk) {
      const int kob = kk * 64 + fq * 16;
      #pragma unroll
      for (int m = 0; m < 4; ++m)
        a[kk][m] = *(const bf16x8*)&si[lds_off(wr * 64 + m * 16 + fr, kob)];
      #pragma unroll
      for (int n = 0; n < 4; ++n)
        b[kk][n] = *(const bf16x8*)&sj[lds_off(wc * 64 + n * 16 + fr, kob)];
    }
  };
  auto mmaInto = [&](f32x4 (&acc)[4][4]) {
    __builtin_amdgcn_s_setprio(1);
    #pragma unroll
    for (int kk = 0; kk < 2; ++kk)
      #pragma unroll
      for (int m = 0; m < 4; ++m)
        #pragma unroll
        for (int n = 0; n < 4; ++n)
          acc[m][n] = __builtin_amdgcn_mfma_f32_16x16x32_bf16(a[kk][m], b[kk][n], acc[m][n], 0, 0, 0);
    __builtin_amdgcn_s_setprio(0);
  };

  stageX(0);          // 8 in flight
  stageY(0);          // 16 in flight
  for (int kt = 0; kt < 7; ++kt) {
    // ---- X phase: wait own X(kt) (leave Y(kt)+... in flight), sync all waves
    asm volatile("s_waitcnt vmcnt(8)" ::: "memory");
    __builtin_amdgcn_s_barrier();
    loadFrags(sXi, sXj);
    asm volatile("s_waitcnt lgkmcnt(0)" ::: "memory");
    __builtin_amdgcn_s_barrier();       // all waves done reading sX -> safe to overwrite
    stageX(kt + 1);                     // overlaps with X MFMAs below
    mmaInto(accK);
    // ---- Y phase
    asm volatile("s_waitcnt vmcnt(8)" ::: "memory");
    __builtin_amdgcn_s_barrier();
    loadFrags(sYi, sYj);
    asm volatile("s_waitcnt lgkmcnt(0)" ::: "memory");
    __builtin_amdgcn_s_barrier();
    stageY(kt + 1);
    mmaInto(accL);
  }
  // ---- epilogue K-step (no further staging)
  asm volatile("s_waitcnt vmcnt(8)" ::: "memory");   // X(7) done, Y(7) in flight
  __builtin_amdgcn_s_barrier();
  loadFrags(sXi, sXj);
  mmaInto(accK);
  asm volatile("s_waitcnt vmcnt(0)" ::: "memory");   // Y(7) done
  __builtin_amdgcn_s_barrier();
  loadFrags(sYi, sYj);
  mmaInto(accL);

  // Epilogue: K = exp(-0.5*max(sq_i + sq_j - 2*G, 0)); off-diag tiles weight 2
  // and contribute column sums.
  float sxj[4], syj[4];
  #pragma unroll
  for (int n = 0; n < 4; ++n) {
    const int j = jb + wc * 64 + n * 16 + fr;
    sxj[n] = sqX[j];
    syj[n] = sqY[j];
  }
  float kl = 0.f;
  float ckK[4] = {0.f, 0.f, 0.f, 0.f}, ckL[4] = {0.f, 0.f, 0.f, 0.f};
  #pragma unroll
  for (int m = 0; m < 4; ++m) {
    #pragma unroll
    for (int r = 0; r < 4; ++r) {
      const int i = ib + wr * 64 + m * 16 + fq * 4 + r;
      const float sxi = sqX[i], syi = sqY[i];
      float rk = 0.f, rl = 0.f;
      #pragma unroll
      for (int n = 0; n < 4; ++n) {
        float dK = fmaxf(sxi + sxj[n] - 2.f * accK[m][n][r], 0.f);
        float Kv = __expf(-0.5f * dK);
        float dL = fmaxf(syi + syj[n] - 2.f * accL[m][n][r], 0.f);
        float Lv = __expf(-0.5f * dL);
        kl += Kv * Lv;
        rk += Kv; rl += Lv;
        ckK[n] += Kv; ckL[n] += Lv;
      }
      #pragma unroll
      for (int msk = 1; msk < 16; msk <<= 1) {
        rk += __shfl_xor(rk, msk);
        rl += __shfl_xor(rl, msk);
      }
      if (fr == 0) {
        atomicAdd(&rowK[i], rk);
        atomicAdd(&rowL[i], rl);
      }
    }
  }
  if (!diag) {
    #pragma unroll
    for (int n = 0; n < 4; ++n) {
      float a2 = ckK[n], b2 = ckL[n];
      a2 += __shfl_xor(a2, 16); a2 += __shfl_xor(a2, 32);
      b2 += __shfl_xor(b2, 16); b2 += __shfl_xor(b2, 32);
      if (fq == 0) {
        const int j = jb + wc * 64 + n * 16 + fr;
        atomicAdd(&rowK[j], a2);
        atomicAdd(&rowL[j], b2);
      }
    }
    kl *= 2.f;
  }
  #pragma unroll
  for (int msk = 1; msk < 64; msk <<= 1) kl += __shfl_xor(kl, msk);
  __shared__ float klred[4];
  if (lane == 0) klred[wave] = kl;
  __syncthreads();
  if (t == 0) atomicAdd(sums, klred[0] + klred[1] + klred[2] + klred[3]);
}

__global__ __launch_bounds__(256) void finalize_kernel(
    const float* __restrict__ rowK, const float* __restrict__ rowL,
    const float* __restrict__ sums, float* __restrict__ out) {
  const int t = threadIdx.x;
  float dp = 0.f, sk = 0.f, sl = 0.f;
  for (int i = t; i < N; i += 256) {
    float a = rowK[i], b = rowL[i];
    dp += a * b; sk += a; sl += b;
  }
  #pragma unroll
  for (int msk = 1; msk < 64; msk <<= 1) {
    dp += __shfl_xor(dp, msk);
    sk += __shfl_xor(sk, msk);
    sl += __shfl_xor(sl, msk);
  }
  __shared__ float r[3][4];
  const int wave = t >> 6, lane = t & 63;
  if (lane == 0) { r[0][wave] = dp; r[1][wave] = sk; r[2][wave] = sl; }
  __syncthreads();
  if (t == 0) {
    float DP = r[0][0] + r[0][1] + r[0][2] + r[0][3];
    float SK = r[1][0] + r[1][1] + r[1][2] + r[1][3];
    float SL = r[2][0] + r[2][1] + r[2][2] + r[2][3];
    const float n = (float)N;
    float raw = sums[0] - (2.f / n) * DP + (SK / n) * (SL / n);
    out[0] = raw / ((n - 1.f) * (n - 1.f));
  }
}

extern "C" void kernel_launch(void* const* d_in, const int* in_sizes, int n_in,
                              void* d_out, int out_size, void* d_ws, size_t ws_size,
                              hipStream_t stream) {
  const float* X = (const float*)d_in[0];
  const float* Y = (const float*)d_in[1];
  char* ws = (char*)d_ws;
  unsigned short* Xb = (unsigned short*)ws;                       // 8 MB
  unsigned short* Yb = (unsigned short*)(ws + (size_t)N * D * 2); // 8 MB
  float* sqX = (float*)(ws + (size_t)N * D * 4);
  float* sqY = sqX + N;
  float* rowK = sqY + N;
  float* rowL = rowK + N;
  float* sums = rowL + N;

  hipMemsetAsync(rowK, 0, (size_t)(2 * N + 16) * sizeof(float), stream);
  prep_kernel<<<2 * N, 128, 0, stream>>>(X, Y, Xb, Yb, sqX, sqY);
  const int ntiles = (N / BM) * (N / BM + 1) / 2;  // 2080 upper-triangle tiles
  hsic_main<<<ntiles, 256, 0, stream>>>(Xb, Yb, sqX, sqY, rowK, rowL, sums);
  finalize_kernel<<<1, 256, 0, stream>>>(rowK, rowL, sums, (float*)d_out);
}